// Round 15
// baseline (219.467 us; speedup 1.0000x reference)
//
#include <hip/hip_runtime.h>
#include <hip/hip_bf16.h>
#include <stdint.h>
#include <stddef.h>

#define T_LEN   2048
#define C_IN_   512
#define D_MODEL_ 1024
#define B_SZ    32

typedef __hip_bfloat16 bf16;
typedef __attribute__((ext_vector_type(8))) short short8;
typedef __attribute__((ext_vector_type(4))) float f32x4;

// ---------------------------------------------------------------------------
// async global->LDS, 16B per lane (linear dest: wave-uniform base + lane*16)
// ---------------------------------------------------------------------------
__device__ __forceinline__ void gload16(const void* g, void* l) {
    __builtin_amdgcn_global_load_lds(
        (const __attribute__((address_space(1))) uint32_t*)g,
        (__attribute__((address_space(3))) uint32_t*)l, 16, 0, 0);
}

// ---------------------------------------------------------------------------
// Kernel 1: W (fp32 [1024][512]) -> bf16, same layout
// ---------------------------------------------------------------------------
__global__ void wconv_kernel(const float* __restrict__ W, bf16* __restrict__ Wb) {
    int i = blockIdx.x * 256 + threadIdx.x;       // 131072 float4 units
    float4 v = ((const float4*)W)[i];
    bf16* o = Wb + (size_t)i * 4;
    o[0] = __float2bfloat16(v.x);
    o[1] = __float2bfloat16(v.y);
    o[2] = __float2bfloat16(v.z);
    o[3] = __float2bfloat16(v.w);
}

// ---------------------------------------------------------------------------
// Kernel 2: bidirectional EWMA (byte-identical to R6 — frozen control)
// ---------------------------------------------------------------------------
__global__ __launch_bounds__(512)
void ewma_kernel(const float* __restrict__ x, bf16* __restrict__ A) {
    const int tid  = threadIdx.x;
    const int wid  = tid >> 6;          // 0..7
    const int lane = tid & 63;
    const int half = lane >> 5;         // 0,1 -> which row of the wave
    const int j    = lane & 31;         // chunk (64 t's each)
    const int b    = blockIdx.x >> 5;   // 0..31
    const int cg   = blockIdx.x & 31;   // 0..31 (16 channels per block)
    const int c_local = (wid << 1) | half;       // 0..15

    const float AL = 0.1f, OM = 0.9f;
    const float Q  = 1.179018457773862e-3f;      // 0.9^64

    __shared__ float buf[8 * 2048];              // 64KB: 8 rows x 8KB
    __shared__ bf16  stg[32 * 16 * 16];          // 16KB output stage

    float xr[64];
    const size_t xbase = ((size_t)b * C_IN_ + (cg << 4)) * T_LEN;
    const int srcu = tid ^ ((tid >> 4) & 7);     // involution on 16B units

    // ---- P1: two halves of 8 channel-rows through LDS
    #pragma unroll
    for (int h = 0; h < 2; ++h) {
        #pragma unroll
        for (int it = 0; it < 8; ++it)
            gload16(x + xbase + (size_t)(h * 8 + it) * T_LEN + srcu * 4,
                    (char*)buf + it * 8192 + tid * 16);
        asm volatile("s_waitcnt vmcnt(0)" ::: "memory");
        __syncthreads();
        if ((c_local >> 3) == h) {
            const char* rbase = (const char*)buf + (c_local & 7) * 8192;
            #pragma unroll
            for (int i = 0; i < 16; ++i) {
                int p = (j * 16 + i) ^ (j & 7);
                float4 v = *(const float4*)(rbase + p * 16);
                xr[4*i+0] = v.x; xr[4*i+1] = v.y;
                xr[4*i+2] = v.z; xr[4*i+3] = v.w;
            }
        }
        __syncthreads();                          // pulls drained before reuse
    }

    // ---- P2: local fwd scan
    float g = (j == 0) ? xr[0] : AL * xr[0];
    #pragma unroll
    for (int i = 1; i < 64; ++i) g = fmaf(OM, g, AL * xr[i]);

    // ---- P3: Kogge-Stone carry scan
    float F = g, coef = Q;
    #pragma unroll
    for (int d = 1; d < 32; d <<= 1) {
        float up = __shfl_up(F, d, 32);
        F += (j >= d) ? coef * up : 0.0f;
        coef *= coef;
    }
    float carry = __shfl_up(F, 1, 32);
    if (j == 0) carry = 0.0f;

    // ---- P4: seeded fwd recompute
    xr[0] = (j == 0) ? xr[0] : fmaf(OM, carry, AL * xr[0]);
    #pragma unroll
    for (int i = 1; i < 64; ++i) xr[i] = fmaf(OM, xr[i-1], AL * xr[i]);

    // ---- P5: local bwd scan from f
    float h2;
    {
        float incL = xr[63] - OM * xr[62];
        if (j == 31) incL *= 10.0f;
        h2 = incL;
        #pragma unroll
        for (int i = 62; i >= 1; --i) h2 = fmaf(OM, h2, xr[i] - OM * xr[i-1]);
        float inc0 = (j == 0) ? AL * xr[0] : (xr[0] - OM * carry);
        h2 = fmaf(OM, h2, inc0);
    }

    // ---- P6: bwd carry scan
    float Bv = h2; coef = Q;
    #pragma unroll
    for (int d = 1; d < 32; d <<= 1) {
        float dn = __shfl_down(Bv, d, 32);
        Bv += (j < 32 - d) ? coef * dn : 0.0f;
        coef *= coef;
    }
    float bnext = __shfl_down(Bv, 1, 32);
    if (j == 31) bnext = 0.0f;

    // ---- P7: final bwd recompute + combine
    {
        float bp = bnext;
        float incL = xr[63] - OM * xr[62];
        if (j == 31) incL *= 10.0f;
        float bb = fmaf(OM, bp, incL);
        xr[63] = 0.5f * (xr[63] + bb);
        bp = bb;
        #pragma unroll
        for (int i = 62; i >= 1; --i) {
            float inc = xr[i] - OM * xr[i-1];
            bb = fmaf(OM, bp, inc);
            xr[i] = 0.5f * (xr[i] + bb);
            bp = bb;
        }
        float inc0 = (j == 0) ? AL * xr[0] : (xr[0] - OM * carry);
        bb = fmaf(OM, bp, inc0);
        xr[0] = 0.5f * (xr[0] + bb);
    }

    // ---- P8: LDS transpose stage -> coalesced bf16 writes
    const size_t outbase = (size_t)(b * T_LEN) * C_IN_ + (cg << 4);
    #pragma unroll
    for (int grp = 0; grp < 4; ++grp) {
        __syncthreads();
        #pragma unroll
        for (int ii = 0; ii < 16; ++ii) {
            int elem = ((j * 16 + ii) * 16 + c_local) ^ ((j & 7) << 3);
            stg[elem] = __float2bfloat16(xr[grp * 16 + ii]);
        }
        __syncthreads();
        #pragma unroll
        for (int r = 0; r < 2; ++r) {
            int u   = tid * 2 + r;               // 1024 16B-units
            int jj  = u >> 5;
            int ii  = (u >> 1) & 15;
            int hf  = u & 1;
            int elem = ((jj * 16 + ii) * 16 + hf * 8) ^ ((jj & 7) << 3);
            float4 v = *(const float4*)&stg[elem];
            int t = jj * 64 + grp * 16 + ii;
            *(float4*)(A + outbase + (size_t)t * C_IN_ + hf * 8) = v;
        }
    }
}

// ---------------------------------------------------------------------------
// Kernel 3: GEMM  out[m][n] = sum_k A[m][k]*W[n][k] + bias[n]
// R15: flat-A + prefetch. Block 256m x 64n, 4 waves (wave 64x64, acc 64).
// B panel (64 x 512 = 64KB) staged to LDS once (XOR-swizzled), ONE barrier.
// A loaded per-lane straight from L2/L3 (no LDS) with DEPTH-1.5 PREFETCH in
// NAMED register sets (aE/aO, unroll-2) + counted vmcnt(4) — fixes R10's
// VGPR-starved serialization (VGPR=72, no prefetch, 185us). ~140 VGPR at
// __launch_bounds__(256,2); LDS 64KB -> 2 blocks/CU. No per-kt barriers.
// ---------------------------------------------------------------------------
#define MFMA(a, b, c) __builtin_amdgcn_mfma_f32_16x16x32_bf16(a, b, c, 0, 0, 0)

__global__ __launch_bounds__(256, 2)
void gemm_kernel(const bf16* __restrict__ Amat, const bf16* __restrict__ Wb,
                 const float* __restrict__ bias, float* __restrict__ out) {
    constexpr int K = C_IN_, N = D_MODEL_;
    extern __shared__ bf16 lds[];                // 64KB B panel [64][512]
    const int tid = threadIdx.x;
    const int w   = tid >> 6, lane = tid & 63;
    const int lr  = lane & 15, lg = lane >> 4;

    // XCD swizzle: 4096 blocks; nb-major within mb so an mb-panel's 16
    // nb-blocks run concurrently on one XCD (A panel L2/L3-shared).
    int bid = blockIdx.x;
    int xcd = bid & 7, idx = bid >> 3;
    int mb  = xcd * 32 + (idx >> 4);             // 0..255
    int nb  = idx & 15;                          // 0..15
    const int m0 = mb * 256, n0 = nb * 64;

    // ---- prologue: stage B panel, LDS[row][u] = Wb[row][u ^ (row&7)]
    #pragma unroll
    for (int r = 0; r < 16; ++r) {
        int q = tid + r * 256;
        int row = q >> 6, u = q & 63;            // 64 x 16B-units per row
        gload16(Wb + (size_t)(n0 + row) * K + ((u ^ (row & 7)) << 3),
                (char*)lds + q * 16);
    }

    f32x4 acc[4][4];
    #pragma unroll
    for (int f = 0; f < 4; ++f)
        #pragma unroll
        for (int n = 0; n < 4; ++n) acc[f][n] = (f32x4){0.f, 0.f, 0.f, 0.f};

    // wave's 64 m-rows; per-lane A row base (row = f*16+lr, k = kt*32+lg*8)
    const bf16* Ab = Amat + (size_t)(m0 + w * 64 + lr) * K + lg * 8;

    short8 aE0, aE1, aE2, aE3, aO0, aO1, aO2, aO3;

#define GLDE(kt) do {                                                       \
        aE0 = *(const short8*)(Ab + (size_t)  0 * K + (kt) * 32);           \
        aE1 = *(const short8*)(Ab + (size_t) 16 * K + (kt) * 32);           \
        aE2 = *(const short8*)(Ab + (size_t) 32 * K + (kt) * 32);           \
        aE3 = *(const short8*)(Ab + (size_t) 48 * K + (kt) * 32);           \
    } while (0)
#define GLDO(kt) do {                                                       \
        aO0 = *(const short8*)(Ab + (size_t)  0 * K + (kt) * 32);           \
        aO1 = *(const short8*)(Ab + (size_t) 16 * K + (kt) * 32);           \
        aO2 = *(const short8*)(Ab + (size_t) 32 * K + (kt) * 32);           \
        aO3 = *(const short8*)(Ab + (size_t) 48 * K + (kt) * 32);           \
    } while (0)

    GLDE(0);                                     // 4 loads (after 16 B-stage)
    GLDO(1);                                     // 4 loads
    asm volatile("s_waitcnt vmcnt(8)" ::: "memory");   // B landed in LDS
    __syncthreads();                             // the ONLY barrier
    asm volatile("s_waitcnt vmcnt(4)" ::: "memory");   // aE(0) ready

    // ---- K loop: 8 iterations x 2 kts; barrier-free, prefetch depth 1.5
    #pragma unroll
    for (int it = 0; it < 8; ++it) {
        const int kt = 2 * it;
        short8 b0, b1, b2, b3;
        // B frags for kt
        {
            int r0 = 0 * 16 + lr, r1 = 1 * 16 + lr, r2 = 2 * 16 + lr, r3 = 3 * 16 + lr;
            b0 = *(const short8*)((const char*)lds + r0 * 1024 + (((kt * 4 + lg) ^ (r0 & 7)) << 4));
            b1 = *(const short8*)((const char*)lds + r1 * 1024 + (((kt * 4 + lg) ^ (r1 & 7)) << 4));
            b2 = *(const short8*)((const char*)lds + r2 * 1024 + (((kt * 4 + lg) ^ (r2 & 7)) << 4));
            b3 = *(const short8*)((const char*)lds + r3 * 1024 + (((kt * 4 + lg) ^ (r3 & 7)) << 4));
        }
        __builtin_amdgcn_s_setprio(1);
        acc[0][0] = MFMA(aE0, b0, acc[0][0]); acc[0][1] = MFMA(aE0, b1, acc[0][1]);
        acc[0][2] = MFMA(aE0, b2, acc[0][2]); acc[0][3] = MFMA(aE0, b3, acc[0][3]);
        acc[1][0] = MFMA(aE1, b0, acc[1][0]); acc[1][1] = MFMA(aE1, b1, acc[1][1]);
        acc[1][2] = MFMA(aE1, b2, acc[1][2]); acc[1][3] = MFMA(aE1, b3, acc[1][3]);
        acc[2][0] = MFMA(aE2, b0, acc[2][0]); acc[2][1] = MFMA(aE2, b1, acc[2][1]);
        acc[2][2] = MFMA(aE2, b2, acc[2][2]); acc[2][3] = MFMA(aE2, b3, acc[2][3]);
        acc[3][0] = MFMA(aE3, b0, acc[3][0]); acc[3][1] = MFMA(aE3, b1, acc[3][1]);
        acc[3][2] = MFMA(aE3, b2, acc[3][2]); acc[3][3] = MFMA(aE3, b3, acc[3][3]);
        __builtin_amdgcn_s_setprio(0);
        if (it < 7) { GLDE(kt + 2); }            // refill even set
        if (it < 7) asm volatile("s_waitcnt vmcnt(4)" ::: "memory");  // aO rdy
        else        asm volatile("s_waitcnt vmcnt(0)" ::: "memory");

        // B frags for kt+1
        {
            int kk = kt + 1;
            int r0 = 0 * 16 + lr, r1 = 1 * 16 + lr, r2 = 2 * 16 + lr, r3 = 3 * 16 + lr;
            b0 = *(const short8*)((const char*)lds + r0 * 1024 + (((kk * 4 + lg) ^ (r0 & 7)) << 4));
            b1 = *(const short8*)((const char*)lds + r1 * 1024 + (((kk * 4 + lg) ^ (r1 & 7)) << 4));
            b2 = *(const short8*)((const char*)lds + r2 * 1024 + (((kk * 4 + lg) ^ (r2 & 7)) << 4));
            b3 = *(const short8*)((const char*)lds + r3 * 1024 + (((kk * 4 + lg) ^ (r3 & 7)) << 4));
        }
        __builtin_amdgcn_s_setprio(1);
        acc[0][0] = MFMA(aO0, b0, acc[0][0]); acc[0][1] = MFMA(aO0, b1, acc[0][1]);
        acc[0][2] = MFMA(aO0, b2, acc[0][2]); acc[0][3] = MFMA(aO0, b3, acc[0][3]);
        acc[1][0] = MFMA(aO1, b0, acc[1][0]); acc[1][1] = MFMA(aO1, b1, acc[1][1]);
        acc[1][2] = MFMA(aO1, b2, acc[1][2]); acc[1][3] = MFMA(aO1, b3, acc[1][3]);
        acc[2][0] = MFMA(aO2, b0, acc[2][0]); acc[2][1] = MFMA(aO2, b1, acc[2][1]);
        acc[2][2] = MFMA(aO2, b2, acc[2][2]); acc[2][3] = MFMA(aO2, b3, acc[2][3]);
        acc[3][0] = MFMA(aO3, b0, acc[3][0]); acc[3][1] = MFMA(aO3, b1, acc[3][1]);
        acc[3][2] = MFMA(aO3, b2, acc[3][2]); acc[3][3] = MFMA(aO3, b3, acc[3][3]);
        __builtin_amdgcn_s_setprio(0);
        if (it < 7) { GLDO(kt + 3); }            // refill odd set
        if (it < 7) asm volatile("s_waitcnt vmcnt(4)" ::: "memory");  // aE rdy
    }
#undef GLDE
#undef GLDO

    // ---- epilogue: per-wave stores, no barrier
    const int crow = lg << 2;
    #pragma unroll
    for (int nf = 0; nf < 4; ++nf) {
        int col = n0 + nf * 16 + lr;
        float bv = bias[col];
        #pragma unroll
        for (int f = 0; f < 4; ++f) {
            size_t rbase = (size_t)(m0 + w * 64 + f * 16 + crow) * N + col;
            #pragma unroll
            for (int r = 0; r < 4; ++r)
                out[rbase + (size_t)r * N] = acc[f][nf][r] + bv;
        }
    }
}

// ---------------------------------------------------------------------------
extern "C" void kernel_launch(void* const* d_in, const int* in_sizes, int n_in,
                              void* d_out, int out_size, void* d_ws, size_t ws_size,
                              hipStream_t stream) {
    const float* x    = (const float*)d_in[0];
    const float* W    = (const float*)d_in[1];
    const float* bias = (const float*)d_in[2];
    float* out = (float*)d_out;

    bf16* Wb   = (bf16*)d_ws;                          // 1MB
    bf16* Amat = (bf16*)((char*)d_ws + (1 << 21));     // 64MB at +2MB

    hipLaunchKernelGGL(wconv_kernel, dim3(512), dim3(256), 0, stream, W, Wb);
    hipLaunchKernelGGL(ewma_kernel, dim3(B_SZ * 32), dim3(512), 0, stream, x, Amat);
    hipLaunchKernelGGL(gemm_kernel,
                       dim3((B_SZ * T_LEN / 256) * (D_MODEL_ / 64)),
                       dim3(256), 65536, stream, Amat, Wb, bias, out);
}

// Round 16
// 185.205 us; speedup vs baseline: 1.1850x; 1.1850x over previous
//
#include <hip/hip_runtime.h>
#include <hip/hip_bf16.h>
#include <stdint.h>
#include <stddef.h>

#define T_LEN   2048
#define C_IN_   512
#define D_MODEL_ 1024
#define B_SZ    32

typedef __hip_bfloat16 bf16;
typedef __attribute__((ext_vector_type(8))) short short8;
typedef __attribute__((ext_vector_type(4))) float f32x4;

// ---------------------------------------------------------------------------
// async global->LDS, 16B per lane (linear dest: wave-uniform base + lane*16)
// ---------------------------------------------------------------------------
__device__ __forceinline__ void gload16(const void* g, void* l) {
    __builtin_amdgcn_global_load_lds(
        (const __attribute__((address_space(1))) uint32_t*)g,
        (__attribute__((address_space(3))) uint32_t*)l, 16, 0, 0);
}

// ---------------------------------------------------------------------------
// Kernel 1: W (fp32 [1024][512]) -> bf16, same layout
// ---------------------------------------------------------------------------
__global__ void wconv_kernel(const float* __restrict__ W, bf16* __restrict__ Wb) {
    int i = blockIdx.x * 256 + threadIdx.x;       // 131072 float4 units
    float4 v = ((const float4*)W)[i];
    bf16* o = Wb + (size_t)i * 4;
    o[0] = __float2bfloat16(v.x);
    o[1] = __float2bfloat16(v.y);
    o[2] = __float2bfloat16(v.z);
    o[3] = __float2bfloat16(v.w);
}

// ---------------------------------------------------------------------------
// Kernel 2: bidirectional EWMA (byte-identical to R6 — frozen control)
// ---------------------------------------------------------------------------
__global__ __launch_bounds__(512)
void ewma_kernel(const float* __restrict__ x, bf16* __restrict__ A) {
    const int tid  = threadIdx.x;
    const int wid  = tid >> 6;          // 0..7
    const int lane = tid & 63;
    const int half = lane >> 5;         // 0,1 -> which row of the wave
    const int j    = lane & 31;         // chunk (64 t's each)
    const int b    = blockIdx.x >> 5;   // 0..31
    const int cg   = blockIdx.x & 31;   // 0..31 (16 channels per block)
    const int c_local = (wid << 1) | half;       // 0..15

    const float AL = 0.1f, OM = 0.9f;
    const float Q  = 1.179018457773862e-3f;      // 0.9^64

    __shared__ float buf[8 * 2048];              // 64KB: 8 rows x 8KB
    __shared__ bf16  stg[32 * 16 * 16];          // 16KB output stage

    float xr[64];
    const size_t xbase = ((size_t)b * C_IN_ + (cg << 4)) * T_LEN;
    const int srcu = tid ^ ((tid >> 4) & 7);     // involution on 16B units

    // ---- P1: two halves of 8 channel-rows through LDS
    #pragma unroll
    for (int h = 0; h < 2; ++h) {
        #pragma unroll
        for (int it = 0; it < 8; ++it)
            gload16(x + xbase + (size_t)(h * 8 + it) * T_LEN + srcu * 4,
                    (char*)buf + it * 8192 + tid * 16);
        asm volatile("s_waitcnt vmcnt(0)" ::: "memory");
        __syncthreads();
        if ((c_local >> 3) == h) {
            const char* rbase = (const char*)buf + (c_local & 7) * 8192;
            #pragma unroll
            for (int i = 0; i < 16; ++i) {
                int p = (j * 16 + i) ^ (j & 7);
                float4 v = *(const float4*)(rbase + p * 16);
                xr[4*i+0] = v.x; xr[4*i+1] = v.y;
                xr[4*i+2] = v.z; xr[4*i+3] = v.w;
            }
        }
        __syncthreads();                          // pulls drained before reuse
    }

    // ---- P2: local fwd scan
    float g = (j == 0) ? xr[0] : AL * xr[0];
    #pragma unroll
    for (int i = 1; i < 64; ++i) g = fmaf(OM, g, AL * xr[i]);

    // ---- P3: Kogge-Stone carry scan
    float F = g, coef = Q;
    #pragma unroll
    for (int d = 1; d < 32; d <<= 1) {
        float up = __shfl_up(F, d, 32);
        F += (j >= d) ? coef * up : 0.0f;
        coef *= coef;
    }
    float carry = __shfl_up(F, 1, 32);
    if (j == 0) carry = 0.0f;

    // ---- P4: seeded fwd recompute
    xr[0] = (j == 0) ? xr[0] : fmaf(OM, carry, AL * xr[0]);
    #pragma unroll
    for (int i = 1; i < 64; ++i) xr[i] = fmaf(OM, xr[i-1], AL * xr[i]);

    // ---- P5: local bwd scan from f
    float h2;
    {
        float incL = xr[63] - OM * xr[62];
        if (j == 31) incL *= 10.0f;
        h2 = incL;
        #pragma unroll
        for (int i = 62; i >= 1; --i) h2 = fmaf(OM, h2, xr[i] - OM * xr[i-1]);
        float inc0 = (j == 0) ? AL * xr[0] : (xr[0] - OM * carry);
        h2 = fmaf(OM, h2, inc0);
    }

    // ---- P6: bwd carry scan
    float Bv = h2; coef = Q;
    #pragma unroll
    for (int d = 1; d < 32; d <<= 1) {
        float dn = __shfl_down(Bv, d, 32);
        Bv += (j < 32 - d) ? coef * dn : 0.0f;
        coef *= coef;
    }
    float bnext = __shfl_down(Bv, 1, 32);
    if (j == 31) bnext = 0.0f;

    // ---- P7: final bwd recompute + combine
    {
        float bp = bnext;
        float incL = xr[63] - OM * xr[62];
        if (j == 31) incL *= 10.0f;
        float bb = fmaf(OM, bp, incL);
        xr[63] = 0.5f * (xr[63] + bb);
        bp = bb;
        #pragma unroll
        for (int i = 62; i >= 1; --i) {
            float inc = xr[i] - OM * xr[i-1];
            bb = fmaf(OM, bp, inc);
            xr[i] = 0.5f * (xr[i] + bb);
            bp = bb;
        }
        float inc0 = (j == 0) ? AL * xr[0] : (xr[0] - OM * carry);
        bb = fmaf(OM, bp, inc0);
        xr[0] = 0.5f * (xr[0] + bb);
    }

    // ---- P8: LDS transpose stage -> coalesced bf16 writes
    const size_t outbase = (size_t)(b * T_LEN) * C_IN_ + (cg << 4);
    #pragma unroll
    for (int grp = 0; grp < 4; ++grp) {
        __syncthreads();
        #pragma unroll
        for (int ii = 0; ii < 16; ++ii) {
            int elem = ((j * 16 + ii) * 16 + c_local) ^ ((j & 7) << 3);
            stg[elem] = __float2bfloat16(xr[grp * 16 + ii]);
        }
        __syncthreads();
        #pragma unroll
        for (int r = 0; r < 2; ++r) {
            int u   = tid * 2 + r;               // 1024 16B-units
            int jj  = u >> 5;
            int ii  = (u >> 1) & 15;
            int hf  = u & 1;
            int elem = ((jj * 16 + ii) * 16 + hf * 8) ^ ((jj & 7) << 3);
            float4 v = *(const float4*)&stg[elem];
            int t = jj * 64 + grp * 16 + ii;
            *(float4*)(A + outbase + (size_t)t * C_IN_ + hf * 8) = v;
        }
    }
}

// ---------------------------------------------------------------------------
// Kernel 3: GEMM  out[m][n] = sum_k A[m][k]*W[n][k] + bias[n]
// R16: PERSISTENT B-RESIDENT design. Grid 512 (2 blocks/CU, never
// re-dispatched). Block = 4 waves, owns 64 N-cols: B panel [64][512] =
// 64KB staged to LDS ONCE (swizzled, conflict-free: 8 bank-groups, b128
// floor). Then 16 m-tiles x 16 kt = 256 continuous pipeline steps:
// A [128][32] double-buffered via global_load_lds (2 loads/kt, vmcnt(2),
// 2-deep lookahead), epilogue stores interleave into the stream. ONE
// prologue drain per block total (vs 4-16 generation drains in all prior
// ~120us variants); B never restaged (saves 268MB L2->LDS + drains).
// XCD-aware: the 16 nb-blocks of an XCD share each A panel in its L2.
// Wave = 32m x 64n, acc 2x4 f32x4 (AGPR). LDS 80KB -> 2 blocks/CU.
// ---------------------------------------------------------------------------
#define MFMA(a, b, c) __builtin_amdgcn_mfma_f32_16x16x32_bf16(a, b, c, 0, 0, 0)

__global__ __launch_bounds__(256, 2)
void gemm_kernel(const bf16* __restrict__ Amat, const bf16* __restrict__ Wb,
                 const float* __restrict__ bias, float* __restrict__ out) {
    constexpr int K = C_IN_, N = D_MODEL_;
    extern __shared__ bf16 lds[];      // B 64KB @0; A sets @64KB + s*8KB
    const int tid = threadIdx.x;
    const int w   = tid >> 6, lane = tid & 63;
    const int lr  = lane & 15, lg = lane >> 4;

    // block -> (xcd, nb, mslice); m-tiles of one XCD shared by its 16 nb
    const int bid = blockIdx.x;
    const int xcd = bid & 7;
    const int nb  = (bid >> 3) & 15;
    const int msl = bid >> 7;                    // 0..3
    const int n0  = nb * 64;
    const int mtbase = (xcd * 4 + msl) * 16;     // first of 16 m-tiles

    char* Bl = (char*)lds;                       // [64 rows][1024 B]
    auto Al = [&](int s) -> char* { return (char*)lds + 65536 + s * 8192; };

    // ---- stage B panel once: LDS[row][u] holds global unit u^(row&7)
    #pragma unroll
    for (int r = 0; r < 16; ++r) {
        int q = tid + r * 256;
        int row = q >> 6, u = q & 63;
        gload16(Wb + (size_t)(n0 + row) * K + ((u ^ (row & 7)) << 3),
                Bl + q * 16);
    }
    // ---- stage A(g) for g=0,1 : A[128][32], LDS[row][u] = global u^(row&3)
    auto stageA = [&](int g) {
        int mt = g >> 4, kt = g & 15;
        int m0 = (mtbase + mt) * 128;
        char* la = Al(g & 1);
        #pragma unroll
        for (int r = 0; r < 2; ++r) {
            int q = tid + r * 256;
            int row = q >> 2, u = q & 3;
            gload16(Amat + (size_t)(m0 + row) * K + kt * 32 + ((u ^ (row & 3)) << 3),
                    la + q * 16);
        }
    };
    stageA(0);
    stageA(1);
    asm volatile("s_waitcnt vmcnt(2)" ::: "memory");   // B + A(0) landed
    __builtin_amdgcn_s_barrier();

    // per-lane bias values
    const float bv0 = bias[n0 + 0 * 16 + lr];
    const float bv1 = bias[n0 + 1 * 16 + lr];
    const float bv2 = bias[n0 + 2 * 16 + lr];
    const float bv3 = bias[n0 + 3 * 16 + lr];

    const int arow0 = w * 32 + lr;               // A frag rows f=0,1 -> +16
    const int crow  = lg << 2;

    #pragma unroll 1
    for (int mt = 0; mt < 16; ++mt) {
        f32x4 acc[2][4];
        #pragma unroll
        for (int f = 0; f < 2; ++f)
            #pragma unroll
            for (int n = 0; n < 4; ++n) acc[f][n] = (f32x4){0.f, 0.f, 0.f, 0.f};

        #pragma unroll
        for (int kt = 0; kt < 16; ++kt) {
            const int s = kt & 1;
            const char* la = Al(s);
            short8 a0, a1, b0, b1, b2, b3;
            {
                int r0 = arow0, r1 = arow0 + 16;
                a0 = *(const short8*)(la + r0 * 64 + ((lg ^ (r0 & 3)) << 4));
                a1 = *(const short8*)(la + r1 * 64 + ((lg ^ (r1 & 3)) << 4));
                int q0 = 0 * 16 + lr, q1 = 1 * 16 + lr, q2 = 2 * 16 + lr, q3 = 3 * 16 + lr;
                int ku = kt * 4 + lg;
                b0 = *(const short8*)(Bl + q0 * 1024 + ((ku ^ (q0 & 7)) << 4));
                b1 = *(const short8*)(Bl + q1 * 1024 + ((ku ^ (q1 & 7)) << 4));
                b2 = *(const short8*)(Bl + q2 * 1024 + ((ku ^ (q2 & 7)) << 4));
                b3 = *(const short8*)(Bl + q3 * 1024 + ((ku ^ (q3 & 7)) << 4));
            }
            asm volatile("s_waitcnt lgkmcnt(0)");
            __builtin_amdgcn_sched_barrier(0);
            __builtin_amdgcn_s_barrier();        // all reads of set s done

            if (mt < 15 || kt < 14) stageA(mt * 16 + kt + 2);  // refill set s

            __builtin_amdgcn_s_setprio(1);
            acc[0][0] = MFMA(a0, b0, acc[0][0]); acc[0][1] = MFMA(a0, b1, acc[0][1]);
            acc[0][2] = MFMA(a0, b2, acc[0][2]); acc[0][3] = MFMA(a0, b3, acc[0][3]);
            acc[1][0] = MFMA(a1, b0, acc[1][0]); acc[1][1] = MFMA(a1, b1, acc[1][1]);
            acc[1][2] = MFMA(a1, b2, acc[1][2]); acc[1][3] = MFMA(a1, b3, acc[1][3]);
            __builtin_amdgcn_s_setprio(0);

            if (mt < 15 || kt < 14)
                asm volatile("s_waitcnt vmcnt(2)" ::: "memory");   // A(g+1) in
            else
                asm volatile("s_waitcnt vmcnt(0)" ::: "memory");   // tail
            __builtin_amdgcn_s_barrier();        // set s^1 ready
        }

        // ---- epilogue for m-tile mt (stores drain under next tile's K-loop)
        const int m0 = (mtbase + mt) * 128;
        #pragma unroll
        for (int f = 0; f < 2; ++f) {
            size_t rb = (size_t)(m0 + w * 32 + f * 16 + crow) * N + n0 + lr;
            #pragma unroll
            for (int r = 0; r < 4; ++r) {
                out[rb + (size_t)r * N +  0] = acc[f][0][r] + bv0;
                out[rb + (size_t)r * N + 16] = acc[f][1][r] + bv1;
                out[rb + (size_t)r * N + 32] = acc[f][2][r] + bv2;
                out[rb + (size_t)r * N + 48] = acc[f][3][r] + bv3;
            }
        }
    }
}

// ---------------------------------------------------------------------------
extern "C" void kernel_launch(void* const* d_in, const int* in_sizes, int n_in,
                              void* d_out, int out_size, void* d_ws, size_t ws_size,
                              hipStream_t stream) {
    const float* x    = (const float*)d_in[0];
    const float* W    = (const float*)d_in[1];
    const float* bias = (const float*)d_in[2];
    float* out = (float*)d_out;

    bf16* Wb   = (bf16*)d_ws;                          // 1MB
    bf16* Amat = (bf16*)((char*)d_ws + (1 << 21));     // 64MB at +2MB

    hipLaunchKernelGGL(wconv_kernel, dim3(512), dim3(256), 0, stream, W, Wb);
    hipLaunchKernelGGL(ewma_kernel, dim3(B_SZ * 32), dim3(512), 0, stream, x, Amat);
    hipLaunchKernelGGL(gemm_kernel, dim3(512), dim3(256), 81920, stream,
                       Amat, Wb, bias, out);
}

// Round 17
// 169.160 us; speedup vs baseline: 1.2974x; 1.0949x over previous
//
#include <hip/hip_runtime.h>
#include <hip/hip_bf16.h>
#include <stdint.h>
#include <stddef.h>

#define T_LEN   2048
#define C_IN_   512
#define D_MODEL_ 1024
#define B_SZ    32

typedef __hip_bfloat16 bf16;
typedef __attribute__((ext_vector_type(8))) short short8;
typedef __attribute__((ext_vector_type(4))) float f32x4;

// ---------------------------------------------------------------------------
// async global->LDS, 16B per lane (linear dest: wave-uniform base + lane*16)
// ---------------------------------------------------------------------------
__device__ __forceinline__ void gload16(const void* g, void* l) {
    __builtin_amdgcn_global_load_lds(
        (const __attribute__((address_space(1))) uint32_t*)g,
        (__attribute__((address_space(3))) uint32_t*)l, 16, 0, 0);
}

// ---------------------------------------------------------------------------
// Kernel 1: W (fp32 [1024][512]) -> bf16, same layout
// ---------------------------------------------------------------------------
__global__ void wconv_kernel(const float* __restrict__ W, bf16* __restrict__ Wb) {
    int i = blockIdx.x * 256 + threadIdx.x;       // 131072 float4 units
    float4 v = ((const float4*)W)[i];
    bf16* o = Wb + (size_t)i * 4;
    o[0] = __float2bfloat16(v.x);
    o[1] = __float2bfloat16(v.y);
    o[2] = __float2bfloat16(v.z);
    o[3] = __float2bfloat16(v.w);
}

// ---------------------------------------------------------------------------
// Kernel 2: bidirectional EWMA (byte-identical to R6 — frozen control)
// ---------------------------------------------------------------------------
__global__ __launch_bounds__(512)
void ewma_kernel(const float* __restrict__ x, bf16* __restrict__ A) {
    const int tid  = threadIdx.x;
    const int wid  = tid >> 6;          // 0..7
    const int lane = tid & 63;
    const int half = lane >> 5;         // 0,1 -> which row of the wave
    const int j    = lane & 31;         // chunk (64 t's each)
    const int b    = blockIdx.x >> 5;   // 0..31
    const int cg   = blockIdx.x & 31;   // 0..31 (16 channels per block)
    const int c_local = (wid << 1) | half;       // 0..15

    const float AL = 0.1f, OM = 0.9f;
    const float Q  = 1.179018457773862e-3f;      // 0.9^64

    __shared__ float buf[8 * 2048];              // 64KB: 8 rows x 8KB
    __shared__ bf16  stg[32 * 16 * 16];          // 16KB output stage

    float xr[64];
    const size_t xbase = ((size_t)b * C_IN_ + (cg << 4)) * T_LEN;
    const int srcu = tid ^ ((tid >> 4) & 7);     // involution on 16B units

    // ---- P1: two halves of 8 channel-rows through LDS
    #pragma unroll
    for (int h = 0; h < 2; ++h) {
        #pragma unroll
        for (int it = 0; it < 8; ++it)
            gload16(x + xbase + (size_t)(h * 8 + it) * T_LEN + srcu * 4,
                    (char*)buf + it * 8192 + tid * 16);
        asm volatile("s_waitcnt vmcnt(0)" ::: "memory");
        __syncthreads();
        if ((c_local >> 3) == h) {
            const char* rbase = (const char*)buf + (c_local & 7) * 8192;
            #pragma unroll
            for (int i = 0; i < 16; ++i) {
                int p = (j * 16 + i) ^ (j & 7);
                float4 v = *(const float4*)(rbase + p * 16);
                xr[4*i+0] = v.x; xr[4*i+1] = v.y;
                xr[4*i+2] = v.z; xr[4*i+3] = v.w;
            }
        }
        __syncthreads();                          // pulls drained before reuse
    }

    // ---- P2: local fwd scan
    float g = (j == 0) ? xr[0] : AL * xr[0];
    #pragma unroll
    for (int i = 1; i < 64; ++i) g = fmaf(OM, g, AL * xr[i]);

    // ---- P3: Kogge-Stone carry scan
    float F = g, coef = Q;
    #pragma unroll
    for (int d = 1; d < 32; d <<= 1) {
        float up = __shfl_up(F, d, 32);
        F += (j >= d) ? coef * up : 0.0f;
        coef *= coef;
    }
    float carry = __shfl_up(F, 1, 32);
    if (j == 0) carry = 0.0f;

    // ---- P4: seeded fwd recompute
    xr[0] = (j == 0) ? xr[0] : fmaf(OM, carry, AL * xr[0]);
    #pragma unroll
    for (int i = 1; i < 64; ++i) xr[i] = fmaf(OM, xr[i-1], AL * xr[i]);

    // ---- P5: local bwd scan from f
    float h2;
    {
        float incL = xr[63] - OM * xr[62];
        if (j == 31) incL *= 10.0f;
        h2 = incL;
        #pragma unroll
        for (int i = 62; i >= 1; --i) h2 = fmaf(OM, h2, xr[i] - OM * xr[i-1]);
        float inc0 = (j == 0) ? AL * xr[0] : (xr[0] - OM * carry);
        h2 = fmaf(OM, h2, inc0);
    }

    // ---- P6: bwd carry scan
    float Bv = h2; coef = Q;
    #pragma unroll
    for (int d = 1; d < 32; d <<= 1) {
        float dn = __shfl_down(Bv, d, 32);
        Bv += (j < 32 - d) ? coef * dn : 0.0f;
        coef *= coef;
    }
    float bnext = __shfl_down(Bv, 1, 32);
    if (j == 31) bnext = 0.0f;

    // ---- P7: final bwd recompute + combine
    {
        float bp = bnext;
        float incL = xr[63] - OM * xr[62];
        if (j == 31) incL *= 10.0f;
        float bb = fmaf(OM, bp, incL);
        xr[63] = 0.5f * (xr[63] + bb);
        bp = bb;
        #pragma unroll
        for (int i = 62; i >= 1; --i) {
            float inc = xr[i] - OM * xr[i-1];
            bb = fmaf(OM, bp, inc);
            xr[i] = 0.5f * (xr[i] + bb);
            bp = bb;
        }
        float inc0 = (j == 0) ? AL * xr[0] : (xr[0] - OM * carry);
        bb = fmaf(OM, bp, inc0);
        xr[0] = 0.5f * (xr[0] + bb);
    }

    // ---- P8: LDS transpose stage -> coalesced bf16 writes
    const size_t outbase = (size_t)(b * T_LEN) * C_IN_ + (cg << 4);
    #pragma unroll
    for (int grp = 0; grp < 4; ++grp) {
        __syncthreads();
        #pragma unroll
        for (int ii = 0; ii < 16; ++ii) {
            int elem = ((j * 16 + ii) * 16 + c_local) ^ ((j & 7) << 3);
            stg[elem] = __float2bfloat16(xr[grp * 16 + ii]);
        }
        __syncthreads();
        #pragma unroll
        for (int r = 0; r < 2; ++r) {
            int u   = tid * 2 + r;               // 1024 16B-units
            int jj  = u >> 5;
            int ii  = (u >> 1) & 15;
            int hf  = u & 1;
            int elem = ((jj * 16 + ii) * 16 + hf * 8) ^ ((jj & 7) << 3);
            float4 v = *(const float4*)&stg[elem];
            int t = jj * 64 + grp * 16 + ii;
            *(float4*)(A + outbase + (size_t)t * C_IN_ + hf * 8) = v;
        }
    }
}

// ---------------------------------------------------------------------------
// Kernel 3: GEMM  out[m][n] = sum_k A[m][k]*W[n][k] + bias[n]
// R17: R11's exact verified geometry (128x128 tile, BK=32, 4 waves 2x2,
// same swizzles/epilogue) with FOUR LDS sets and a 3-kt-ahead staging
// stream. Rationale: every prior variant gave staged loads a deadline
// (vmcnt checkpoint distance) of <= 1 kt ~ 160 MFMA-cycles, below the
// 200-900cyc L2/L3 latency (m126) -> every kt exposed latency, in every
// schedule, at every occupancy (the invariant 120us). Here: prologue
// stages kt0-2; iter kt stages kt+3; checkpoint vmcnt(8) leaves 2 full
// kt-tiles outstanding -> each load has a 2-iteration (~350-500cyc)
// deadline >= latency. One barrier/kt (4-set rotation: stage targets the
// set last read at kt-1, sealed by kt-1's barrier). LDS 4x16KB = 64KB ->
// 2 blocks/CU; VGPR ~110 <= 128 @ (256,2)... using (256,2) to be safe.
// ---------------------------------------------------------------------------
#define MFMA(a, b, c) __builtin_amdgcn_mfma_f32_16x16x32_bf16(a, b, c, 0, 0, 0)

__global__ __launch_bounds__(256, 2)
void gemm_kernel(const bf16* __restrict__ Amat, const bf16* __restrict__ Wb,
                 const float* __restrict__ bias, float* __restrict__ out) {
    constexpr int K = C_IN_, N = D_MODEL_;
    extern __shared__ bf16 lds[];                // 4 sets x (A 8KB + B 8KB)
    const int tid  = threadIdx.x;
    const int wid  = tid >> 6, lane = tid & 63;
    const int wr   = wid >> 1, wc = wid & 1;     // 2x2 wave grid, wave 64x64
    const int lr   = lane & 15;
    const int lg   = lane >> 4;

    // T1: bijective XCD swizzle (4096 blocks); 8 nb share each A panel
    int bid = blockIdx.x;
    int swz = (bid & 7) * 512 + (bid >> 3);
    const int mb = swz >> 3, nb = swz & 7;       // 512 x 8
    const int m0 = mb * 128, n0 = nb * 128;

    // set s at byte s*16384: A 8KB then B 8KB
    auto stage = [&](int kt) {
        const int s = kt & 3;
        char* la = (char*)lds + s * 16384;
        char* lb = la + 8192;
        #pragma unroll
        for (int r = 0; r < 2; ++r) {
            int q = tid + r * 256;
            int row = q >> 2, u = q & 3;
            gload16(Amat + (size_t)(m0 + row) * K + kt * 32 + ((u ^ ((row >> 1) & 3)) << 3),
                    la + q * 16);
        }
        #pragma unroll
        for (int r = 0; r < 2; ++r) {
            int q = tid + r * 256;
            int row = q >> 2, u = q & 3;
            gload16(Wb + (size_t)(n0 + row) * K + kt * 32 + ((u ^ ((row >> 1) & 3)) << 3),
                    lb + q * 16);
        }
    };
    auto rdA = [&](int s, int f) -> short8 {
        int row = wr * 64 + f * 16 + lr;
        return *(const short8*)((const char*)lds + s * 16384
                                + row * 64 + ((lg ^ ((row >> 1) & 3)) << 4));
    };
    auto rdB = [&](int s, int n) -> short8 {
        int row = wc * 64 + n * 16 + lr;
        return *(const short8*)((const char*)lds + s * 16384 + 8192
                                + row * 64 + ((lg ^ ((row >> 1) & 3)) << 4));
    };

    f32x4 acc[4][4];
    #pragma unroll
    for (int f = 0; f < 4; ++f)
        #pragma unroll
        for (int n = 0; n < 4; ++n) acc[f][n] = (f32x4){0.f, 0.f, 0.f, 0.f};

    // ---- prologue: stage kt 0,1,2 (12 loads); wait kt0 (leave 8)
    stage(0);
    stage(1);
    stage(2);
    asm volatile("s_waitcnt vmcnt(8)" ::: "memory");
    __builtin_amdgcn_s_barrier();

    // ---- K loop: 16 K-tiles of 32; 3-kt lookahead, vmcnt(8) checkpoints
    #pragma unroll
    for (int kt = 0; kt < 16; ++kt) {
        const int s = kt & 3;
        short8 a[4], b[4];
        #pragma unroll
        for (int f = 0; f < 4; ++f) a[f] = rdA(s, f);
        #pragma unroll
        for (int n = 0; n < 4; ++n) b[n] = rdB(s, n);

        if (kt < 13) stage(kt + 3);              // set (kt+3)&3: read done @kt-1

        asm volatile("s_waitcnt lgkmcnt(0)");
        __builtin_amdgcn_sched_barrier(0);

        __builtin_amdgcn_s_setprio(1);
        #pragma unroll
        for (int f = 0; f < 4; ++f)
            #pragma unroll
            for (int n = 0; n < 4; ++n)
                acc[f][n] = MFMA(a[f], b[n], acc[f][n]);
        __builtin_amdgcn_s_setprio(0);

        // ensure stage(kt+1) landed before next iter reads it
        if (kt < 13)       asm volatile("s_waitcnt vmcnt(8)" ::: "memory");
        else if (kt == 13) asm volatile("s_waitcnt vmcnt(4)" ::: "memory");
        else if (kt == 14) asm volatile("s_waitcnt vmcnt(0)" ::: "memory");
        __builtin_amdgcn_s_barrier();
    }

    // ---- epilogue: C write + bias (fp32)
    const int crow = lg << 2;
    #pragma unroll
    for (int n = 0; n < 4; ++n) {
        int col = n0 + wc * 64 + n * 16 + lr;
        float bv = bias[col];
        #pragma unroll
        for (int f = 0; f < 4; ++f) {
            size_t rbase = (size_t)(m0 + wr * 64 + f * 16 + crow) * N + col;
            #pragma unroll
            for (int r = 0; r < 4; ++r)
                out[rbase + (size_t)r * N] = acc[f][n][r] + bv;
        }
    }
}

// ---------------------------------------------------------------------------
extern "C" void kernel_launch(void* const* d_in, const int* in_sizes, int n_in,
                              void* d_out, int out_size, void* d_ws, size_t ws_size,
                              hipStream_t stream) {
    const float* x    = (const float*)d_in[0];
    const float* W    = (const float*)d_in[1];
    const float* bias = (const float*)d_in[2];
    float* out = (float*)d_out;

    bf16* Wb   = (bf16*)d_ws;                          // 1MB
    bf16* Amat = (bf16*)((char*)d_ws + (1 << 21));     // 64MB at +2MB

    hipLaunchKernelGGL(wconv_kernel, dim3(512), dim3(256), 0, stream, W, Wb);
    hipLaunchKernelGGL(ewma_kernel, dim3(B_SZ * 32), dim3(512), 0, stream, x, Amat);
    hipLaunchKernelGGL(gemm_kernel,
                       dim3((B_SZ * T_LEN / 128) * (D_MODEL_ / 128)),
                       dim3(256), 65536, stream, Amat, Wb, bias, out);
}

// Round 19
// 166.545 us; speedup vs baseline: 1.3178x; 1.0157x over previous
//
#include <hip/hip_runtime.h>
#include <hip/hip_bf16.h>
#include <stdint.h>
#include <stddef.h>

#define T_LEN   2048
#define C_IN_   512
#define D_MODEL_ 1024
#define B_SZ    32

typedef __hip_bfloat16 bf16;
typedef __attribute__((ext_vector_type(8))) short short8;
typedef __attribute__((ext_vector_type(4))) float f32x4;

// ---------------------------------------------------------------------------
// async global->LDS, 16B per lane (linear dest: wave-uniform base + lane*16)
// ---------------------------------------------------------------------------
__device__ __forceinline__ void gload16(const void* g, void* l) {
    __builtin_amdgcn_global_load_lds(
        (const __attribute__((address_space(1))) uint32_t*)g,
        (__attribute__((address_space(3))) uint32_t*)l, 16, 0, 0);
}

// ---------------------------------------------------------------------------
// Kernel 1: bidirectional EWMA (R6 body, frozen) + FUSED W->bf16 conversion.
// R19: R18's fusion with the indexing FIXED: W = 524288 floats = 131072
// float4 units; only blocks 0..255 convert (256 x 512 threads = 131072
// units, 1/thread). R18 dispatched 4x too many -> OOB read of W (fault)
// and OOB write of Wb into the Amat region.
// ---------------------------------------------------------------------------
__global__ __launch_bounds__(512)
void ewma_kernel(const float* __restrict__ x, const float* __restrict__ W,
                 bf16* __restrict__ Wb, bf16* __restrict__ A) {
    const int tid  = threadIdx.x;
    const int wid  = tid >> 6;          // 0..7
    const int lane = tid & 63;
    const int half = lane >> 5;         // 0,1 -> which row of the wave
    const int j    = lane & 31;         // chunk (64 t's each)
    const int b    = blockIdx.x >> 5;   // 0..31
    const int cg   = blockIdx.x & 31;   // 0..31 (16 channels per block)
    const int c_local = (wid << 1) | half;       // 0..15

    const float AL = 0.1f, OM = 0.9f;
    const float Q  = 1.179018457773862e-3f;      // 0.9^64

    __shared__ float buf[8 * 2048];              // 64KB: 8 rows x 8KB
    __shared__ bf16  stg[32 * 16 * 16];          // 16KB output stage

    // ---- fused wconv: blocks 0..255 convert one float4 unit per thread
    if (blockIdx.x < 256) {
        int u = blockIdx.x * 512 + tid;          // 0..131071 (= all of W)
        float4 v = ((const float4*)W)[u];
        bf16* o = Wb + (size_t)u * 4;
        o[0] = __float2bfloat16(v.x);
        o[1] = __float2bfloat16(v.y);
        o[2] = __float2bfloat16(v.z);
        o[3] = __float2bfloat16(v.w);
    }

    float xr[64];
    const size_t xbase = ((size_t)b * C_IN_ + (cg << 4)) * T_LEN;
    const int srcu = tid ^ ((tid >> 4) & 7);     // involution on 16B units

    // ---- P1: two halves of 8 channel-rows through LDS
    #pragma unroll
    for (int h = 0; h < 2; ++h) {
        #pragma unroll
        for (int it = 0; it < 8; ++it)
            gload16(x + xbase + (size_t)(h * 8 + it) * T_LEN + srcu * 4,
                    (char*)buf + it * 8192 + tid * 16);
        asm volatile("s_waitcnt vmcnt(0)" ::: "memory");
        __syncthreads();
        if ((c_local >> 3) == h) {
            const char* rbase = (const char*)buf + (c_local & 7) * 8192;
            #pragma unroll
            for (int i = 0; i < 16; ++i) {
                int p = (j * 16 + i) ^ (j & 7);
                float4 v = *(const float4*)(rbase + p * 16);
                xr[4*i+0] = v.x; xr[4*i+1] = v.y;
                xr[4*i+2] = v.z; xr[4*i+3] = v.w;
            }
        }
        __syncthreads();                          // pulls drained before reuse
    }

    // ---- P2: local fwd scan
    float g = (j == 0) ? xr[0] : AL * xr[0];
    #pragma unroll
    for (int i = 1; i < 64; ++i) g = fmaf(OM, g, AL * xr[i]);

    // ---- P3: Kogge-Stone carry scan
    float F = g, coef = Q;
    #pragma unroll
    for (int d = 1; d < 32; d <<= 1) {
        float up = __shfl_up(F, d, 32);
        F += (j >= d) ? coef * up : 0.0f;
        coef *= coef;
    }
    float carry = __shfl_up(F, 1, 32);
    if (j == 0) carry = 0.0f;

    // ---- P4: seeded fwd recompute
    xr[0] = (j == 0) ? xr[0] : fmaf(OM, carry, AL * xr[0]);
    #pragma unroll
    for (int i = 1; i < 64; ++i) xr[i] = fmaf(OM, xr[i-1], AL * xr[i]);

    // ---- P5: local bwd scan from f
    float h2;
    {
        float incL = xr[63] - OM * xr[62];
        if (j == 31) incL *= 10.0f;
        h2 = incL;
        #pragma unroll
        for (int i = 62; i >= 1; --i) h2 = fmaf(OM, h2, xr[i] - OM * xr[i-1]);
        float inc0 = (j == 0) ? AL * xr[0] : (xr[0] - OM * carry);
        h2 = fmaf(OM, h2, inc0);
    }

    // ---- P6: bwd carry scan
    float Bv = h2; coef = Q;
    #pragma unroll
    for (int d = 1; d < 32; d <<= 1) {
        float dn = __shfl_down(Bv, d, 32);
        Bv += (j < 32 - d) ? coef * dn : 0.0f;
        coef *= coef;
    }
    float bnext = __shfl_down(Bv, 1, 32);
    if (j == 31) bnext = 0.0f;

    // ---- P7: final bwd recompute + combine
    {
        float bp = bnext;
        float incL = xr[63] - OM * xr[62];
        if (j == 31) incL *= 10.0f;
        float bb = fmaf(OM, bp, incL);
        xr[63] = 0.5f * (xr[63] + bb);
        bp = bb;
        #pragma unroll
        for (int i = 62; i >= 1; --i) {
            float inc = xr[i] - OM * xr[i-1];
            bb = fmaf(OM, bp, inc);
            xr[i] = 0.5f * (xr[i] + bb);
            bp = bb;
        }
        float inc0 = (j == 0) ? AL * xr[0] : (xr[0] - OM * carry);
        bb = fmaf(OM, bp, inc0);
        xr[0] = 0.5f * (xr[0] + bb);
    }

    // ---- P8: LDS transpose stage -> coalesced bf16 writes
    const size_t outbase = (size_t)(b * T_LEN) * C_IN_ + (cg << 4);
    #pragma unroll
    for (int grp = 0; grp < 4; ++grp) {
        __syncthreads();
        #pragma unroll
        for (int ii = 0; ii < 16; ++ii) {
            int elem = ((j * 16 + ii) * 16 + c_local) ^ ((j & 7) << 3);
            stg[elem] = __float2bfloat16(xr[grp * 16 + ii]);
        }
        __syncthreads();
        #pragma unroll
        for (int r = 0; r < 2; ++r) {
            int u   = tid * 2 + r;               // 1024 16B-units
            int jj  = u >> 5;
            int ii  = (u >> 1) & 15;
            int hf  = u & 1;
            int elem = ((jj * 16 + ii) * 16 + hf * 8) ^ ((jj & 7) << 3);
            float4 v = *(const float4*)&stg[elem];
            int t = jj * 64 + grp * 16 + ii;
            *(float4*)(A + outbase + (size_t)t * C_IN_ + hf * 8) = v;
        }
    }
}

// ---------------------------------------------------------------------------
// Kernel 2: GEMM  out[m][n] = sum_k A[m][k]*W[n][k] + bias[n]
// (byte-identical to R17 — best measured total, 4-set 3-kt-lookahead)
// ---------------------------------------------------------------------------
#define MFMA(a, b, c) __builtin_amdgcn_mfma_f32_16x16x32_bf16(a, b, c, 0, 0, 0)

__global__ __launch_bounds__(256, 2)
void gemm_kernel(const bf16* __restrict__ Amat, const bf16* __restrict__ Wb,
                 const float* __restrict__ bias, float* __restrict__ out) {
    constexpr int K = C_IN_, N = D_MODEL_;
    extern __shared__ bf16 lds[];                // 4 sets x (A 8KB + B 8KB)
    const int tid  = threadIdx.x;
    const int wid  = tid >> 6, lane = tid & 63;
    const int wr   = wid >> 1, wc = wid & 1;     // 2x2 wave grid, wave 64x64
    const int lr   = lane & 15;
    const int lg   = lane >> 4;

    // T1: bijective XCD swizzle (4096 blocks); 8 nb share each A panel
    int bid = blockIdx.x;
    int swz = (bid & 7) * 512 + (bid >> 3);
    const int mb = swz >> 3, nb = swz & 7;       // 512 x 8
    const int m0 = mb * 128, n0 = nb * 128;

    // set s at byte s*16384: A 8KB then B 8KB
    auto stage = [&](int kt) {
        const int s = kt & 3;
        char* la = (char*)lds + s * 16384;
        char* lb = la + 8192;
        #pragma unroll
        for (int r = 0; r < 2; ++r) {
            int q = tid + r * 256;
            int row = q >> 2, u = q & 3;
            gload16(Amat + (size_t)(m0 + row) * K + kt * 32 + ((u ^ ((row >> 1) & 3)) << 3),
                    la + q * 16);
        }
        #pragma unroll
        for (int r = 0; r < 2; ++r) {
            int q = tid + r * 256;
            int row = q >> 2, u = q & 3;
            gload16(Wb + (size_t)(n0 + row) * K + kt * 32 + ((u ^ ((row >> 1) & 3)) << 3),
                    lb + q * 16);
        }
    };
    auto rdA = [&](int s, int f) -> short8 {
        int row = wr * 64 + f * 16 + lr;
        return *(const short8*)((const char*)lds + s * 16384
                                + row * 64 + ((lg ^ ((row >> 1) & 3)) << 4));
    };
    auto rdB = [&](int s, int n) -> short8 {
        int row = wc * 64 + n * 16 + lr;
        return *(const short8*)((const char*)lds + s * 16384 + 8192
                                + row * 64 + ((lg ^ ((row >> 1) & 3)) << 4));
    };

    f32x4 acc[4][4];
    #pragma unroll
    for (int f = 0; f < 4; ++f)
        #pragma unroll
        for (int n = 0; n < 4; ++n) acc[f][n] = (f32x4){0.f, 0.f, 0.f, 0.f};

    // ---- prologue: stage kt 0,1,2 (12 loads); wait kt0 (leave 8)
    stage(0);
    stage(1);
    stage(2);
    asm volatile("s_waitcnt vmcnt(8)" ::: "memory");
    __builtin_amdgcn_s_barrier();

    // ---- K loop: 16 K-tiles of 32; 3-kt lookahead, vmcnt(8) checkpoints
    #pragma unroll
    for (int kt = 0; kt < 16; ++kt) {
        const int s = kt & 3;
        short8 a[4], b[4];
        #pragma unroll
        for (int f = 0; f < 4; ++f) a[f] = rdA(s, f);
        #pragma unroll
        for (int n = 0; n < 4; ++n) b[n] = rdB(s, n);

        if (kt < 13) stage(kt + 3);              // set (kt+3)&3: read done @kt-1

        asm volatile("s_waitcnt lgkmcnt(0)");
        __builtin_amdgcn_sched_barrier(0);

        __builtin_amdgcn_s_setprio(1);
        #pragma unroll
        for (int f = 0; f < 4; ++f)
            #pragma unroll
            for (int n = 0; n < 4; ++n)
                acc[f][n] = MFMA(a[f], b[n], acc[f][n]);
        __builtin_amdgcn_s_setprio(0);

        // ensure stage(kt+1) landed before next iter reads it
        if (kt < 13)       asm volatile("s_waitcnt vmcnt(8)" ::: "memory");
        else if (kt == 13) asm volatile("s_waitcnt vmcnt(4)" ::: "memory");
        else if (kt == 14) asm volatile("s_waitcnt vmcnt(0)" ::: "memory");
        __builtin_amdgcn_s_barrier();
    }

    // ---- epilogue: C write + bias (fp32)
    const int crow = lg << 2;
    #pragma unroll
    for (int n = 0; n < 4; ++n) {
        int col = n0 + wc * 64 + n * 16 + lr;
        float bv = bias[col];
        #pragma unroll
        for (int f = 0; f < 4; ++f) {
            size_t rbase = (size_t)(m0 + wr * 64 + f * 16 + crow) * N + col;
            #pragma unroll
            for (int r = 0; r < 4; ++r)
                out[rbase + (size_t)r * N] = acc[f][n][r] + bv;
        }
    }
}

// ---------------------------------------------------------------------------
extern "C" void kernel_launch(void* const* d_in, const int* in_sizes, int n_in,
                              void* d_out, int out_size, void* d_ws, size_t ws_size,
                              hipStream_t stream) {
    const float* x    = (const float*)d_in[0];
    const float* W    = (const float*)d_in[1];
    const float* bias = (const float*)d_in[2];
    float* out = (float*)d_out;

    bf16* Wb   = (bf16*)d_ws;                          // 1MB
    bf16* Amat = (bf16*)((char*)d_ws + (1 << 21));     // 64MB at +2MB

    hipLaunchKernelGGL(ewma_kernel, dim3(B_SZ * 32), dim3(512), 0, stream,
                       x, W, Wb, Amat);
    hipLaunchKernelGGL(gemm_kernel,
                       dim3((B_SZ * T_LEN / 128) * (D_MODEL_ / 128)),
                       dim3(256), 65536, stream, Amat, Wb, bias, out);
}

// Round 20
// 164.726 us; speedup vs baseline: 1.3323x; 1.0110x over previous
//
#include <hip/hip_runtime.h>
#include <hip/hip_bf16.h>
#include <stdint.h>
#include <stddef.h>

#define T_LEN   2048
#define C_IN_   512
#define D_MODEL_ 1024
#define B_SZ    32

typedef __hip_bfloat16 bf16;
typedef __attribute__((ext_vector_type(8))) short short8;
typedef __attribute__((ext_vector_type(4))) float f32x4;

// ---------------------------------------------------------------------------
// async global->LDS, 16B per lane (linear dest: wave-uniform base + lane*16)
// ---------------------------------------------------------------------------
__device__ __forceinline__ void gload16(const void* g, void* l) {
    __builtin_amdgcn_global_load_lds(
        (const __attribute__((address_space(1))) uint32_t*)g,
        (__attribute__((address_space(3))) uint32_t*)l, 16, 0, 0);
}

// ---------------------------------------------------------------------------
// Kernel 1: bidirectional EWMA (R6 body) + fused W->bf16 (R19, frozen)
// ---------------------------------------------------------------------------
__global__ __launch_bounds__(512)
void ewma_kernel(const float* __restrict__ x, const float* __restrict__ W,
                 bf16* __restrict__ Wb, bf16* __restrict__ A) {
    const int tid  = threadIdx.x;
    const int wid  = tid >> 6;          // 0..7
    const int lane = tid & 63;
    const int half = lane >> 5;         // 0,1 -> which row of the wave
    const int j    = lane & 31;         // chunk (64 t's each)
    const int b    = blockIdx.x >> 5;   // 0..31
    const int cg   = blockIdx.x & 31;   // 0..31 (16 channels per block)
    const int c_local = (wid << 1) | half;       // 0..15

    const float AL = 0.1f, OM = 0.9f;
    const float Q  = 1.179018457773862e-3f;      // 0.9^64

    __shared__ float buf[8 * 2048];              // 64KB: 8 rows x 8KB
    __shared__ bf16  stg[32 * 16 * 16];          // 16KB output stage

    // ---- fused wconv: blocks 0..255 convert one float4 unit per thread
    if (blockIdx.x < 256) {
        int u = blockIdx.x * 512 + tid;          // 0..131071 (= all of W)
        float4 v = ((const float4*)W)[u];
        bf16* o = Wb + (size_t)u * 4;
        o[0] = __float2bfloat16(v.x);
        o[1] = __float2bfloat16(v.y);
        o[2] = __float2bfloat16(v.z);
        o[3] = __float2bfloat16(v.w);
    }

    float xr[64];
    const size_t xbase = ((size_t)b * C_IN_ + (cg << 4)) * T_LEN;
    const int srcu = tid ^ ((tid >> 4) & 7);     // involution on 16B units

    // ---- P1: two halves of 8 channel-rows through LDS
    #pragma unroll
    for (int h = 0; h < 2; ++h) {
        #pragma unroll
        for (int it = 0; it < 8; ++it)
            gload16(x + xbase + (size_t)(h * 8 + it) * T_LEN + srcu * 4,
                    (char*)buf + it * 8192 + tid * 16);
        asm volatile("s_waitcnt vmcnt(0)" ::: "memory");
        __syncthreads();
        if ((c_local >> 3) == h) {
            const char* rbase = (const char*)buf + (c_local & 7) * 8192;
            #pragma unroll
            for (int i = 0; i < 16; ++i) {
                int p = (j * 16 + i) ^ (j & 7);
                float4 v = *(const float4*)(rbase + p * 16);
                xr[4*i+0] = v.x; xr[4*i+1] = v.y;
                xr[4*i+2] = v.z; xr[4*i+3] = v.w;
            }
        }
        __syncthreads();                          // pulls drained before reuse
    }

    // ---- P2: local fwd scan
    float g = (j == 0) ? xr[0] : AL * xr[0];
    #pragma unroll
    for (int i = 1; i < 64; ++i) g = fmaf(OM, g, AL * xr[i]);

    // ---- P3: Kogge-Stone carry scan
    float F = g, coef = Q;
    #pragma unroll
    for (int d = 1; d < 32; d <<= 1) {
        float up = __shfl_up(F, d, 32);
        F += (j >= d) ? coef * up : 0.0f;
        coef *= coef;
    }
    float carry = __shfl_up(F, 1, 32);
    if (j == 0) carry = 0.0f;

    // ---- P4: seeded fwd recompute
    xr[0] = (j == 0) ? xr[0] : fmaf(OM, carry, AL * xr[0]);
    #pragma unroll
    for (int i = 1; i < 64; ++i) xr[i] = fmaf(OM, xr[i-1], AL * xr[i]);

    // ---- P5: local bwd scan from f
    float h2;
    {
        float incL = xr[63] - OM * xr[62];
        if (j == 31) incL *= 10.0f;
        h2 = incL;
        #pragma unroll
        for (int i = 62; i >= 1; --i) h2 = fmaf(OM, h2, xr[i] - OM * xr[i-1]);
        float inc0 = (j == 0) ? AL * xr[0] : (xr[0] - OM * carry);
        h2 = fmaf(OM, h2, inc0);
    }

    // ---- P6: bwd carry scan
    float Bv = h2; coef = Q;
    #pragma unroll
    for (int d = 1; d < 32; d <<= 1) {
        float dn = __shfl_down(Bv, d, 32);
        Bv += (j < 32 - d) ? coef * dn : 0.0f;
        coef *= coef;
    }
    float bnext = __shfl_down(Bv, 1, 32);
    if (j == 31) bnext = 0.0f;

    // ---- P7: final bwd recompute + combine
    {
        float bp = bnext;
        float incL = xr[63] - OM * xr[62];
        if (j == 31) incL *= 10.0f;
        float bb = fmaf(OM, bp, incL);
        xr[63] = 0.5f * (xr[63] + bb);
        bp = bb;
        #pragma unroll
        for (int i = 62; i >= 1; --i) {
            float inc = xr[i] - OM * xr[i-1];
            bb = fmaf(OM, bp, inc);
            xr[i] = 0.5f * (xr[i] + bb);
            bp = bb;
        }
        float inc0 = (j == 0) ? AL * xr[0] : (xr[0] - OM * carry);
        bb = fmaf(OM, bp, inc0);
        xr[0] = 0.5f * (xr[0] + bb);
    }

    // ---- P8: LDS transpose stage -> coalesced bf16 writes
    const size_t outbase = (size_t)(b * T_LEN) * C_IN_ + (cg << 4);
    #pragma unroll
    for (int grp = 0; grp < 4; ++grp) {
        __syncthreads();
        #pragma unroll
        for (int ii = 0; ii < 16; ++ii) {
            int elem = ((j * 16 + ii) * 16 + c_local) ^ ((j & 7) << 3);
            stg[elem] = __float2bfloat16(xr[grp * 16 + ii]);
        }
        __syncthreads();
        #pragma unroll
        for (int r = 0; r < 2; ++r) {
            int u   = tid * 2 + r;               // 1024 16B-units
            int jj  = u >> 5;
            int ii  = (u >> 1) & 15;
            int hf  = u & 1;
            int elem = ((jj * 16 + ii) * 16 + hf * 8) ^ ((jj & 7) << 3);
            float4 v = *(const float4*)&stg[elem];
            int t = jj * 64 + grp * 16 + ii;
            *(float4*)(A + outbase + (size_t)t * C_IN_ + hf * 8) = v;
        }
    }
}

// ---------------------------------------------------------------------------
// Kernel 2: GEMM  out[m][n] = sum_k A[m][k]*W[n][k] + bias[n]
// R20: R17's 4-set 3-kt-lookahead geometry with the HAND-PINNING REMOVED.
// Every prior structure had `lgkmcnt(0)+sched_barrier(0)` between the frag
// reads and the MFMA cluster — the m141 anti-pattern: it forces a full LDS
// drain before the FIRST MFMA, defeating the compiler's fine-grained
// lgkmcnt(4/3/1/0) read/MFMA interleave (the thing m97's 874TF relies on).
// Here the reads are plain loads and the compiler schedules them; counted
// vmcnt checkpoints for the gload_lds pipeline remain (they don't touch
// lgkm). WAR at the barrier is sealed because all 8 reads are consumed by
// the MFMA cluster before the barrier.
// ---------------------------------------------------------------------------
#define MFMA(a, b, c) __builtin_amdgcn_mfma_f32_16x16x32_bf16(a, b, c, 0, 0, 0)

__global__ __launch_bounds__(256, 2)
void gemm_kernel(const bf16* __restrict__ Amat, const bf16* __restrict__ Wb,
                 const float* __restrict__ bias, float* __restrict__ out) {
    constexpr int K = C_IN_, N = D_MODEL_;
    extern __shared__ bf16 lds[];                // 4 sets x (A 8KB + B 8KB)
    const int tid  = threadIdx.x;
    const int wid  = tid >> 6, lane = tid & 63;
    const int wr   = wid >> 1, wc = wid & 1;     // 2x2 wave grid, wave 64x64
    const int lr   = lane & 15;
    const int lg   = lane >> 4;

    // T1: bijective XCD swizzle (4096 blocks); 8 nb share each A panel
    int bid = blockIdx.x;
    int swz = (bid & 7) * 512 + (bid >> 3);
    const int mb = swz >> 3, nb = swz & 7;       // 512 x 8
    const int m0 = mb * 128, n0 = nb * 128;

    // set s at byte s*16384: A 8KB then B 8KB
    auto stage = [&](int kt) {
        const int s = kt & 3;
        char* la = (char*)lds + s * 16384;
        char* lb = la + 8192;
        #pragma unroll
        for (int r = 0; r < 2; ++r) {
            int q = tid + r * 256;
            int row = q >> 2, u = q & 3;
            gload16(Amat + (size_t)(m0 + row) * K + kt * 32 + ((u ^ ((row >> 1) & 3)) << 3),
                    la + q * 16);
        }
        #pragma unroll
        for (int r = 0; r < 2; ++r) {
            int q = tid + r * 256;
            int row = q >> 2, u = q & 3;
            gload16(Wb + (size_t)(n0 + row) * K + kt * 32 + ((u ^ ((row >> 1) & 3)) << 3),
                    lb + q * 16);
        }
    };
    auto rdA = [&](int s, int f) -> short8 {
        int row = wr * 64 + f * 16 + lr;
        return *(const short8*)((const char*)lds + s * 16384
                                + row * 64 + ((lg ^ ((row >> 1) & 3)) << 4));
    };
    auto rdB = [&](int s, int n) -> short8 {
        int row = wc * 64 + n * 16 + lr;
        return *(const short8*)((const char*)lds + s * 16384 + 8192
                                + row * 64 + ((lg ^ ((row >> 1) & 3)) << 4));
    };

    f32x4 acc[4][4];
    #pragma unroll
    for (int f = 0; f < 4; ++f)
        #pragma unroll
        for (int n = 0; n < 4; ++n) acc[f][n] = (f32x4){0.f, 0.f, 0.f, 0.f};

    // ---- prologue: stage kt 0,1,2 (12 loads); wait kt0 (leave 8)
    stage(0);
    stage(1);
    stage(2);
    asm volatile("s_waitcnt vmcnt(8)" ::: "memory");
    __builtin_amdgcn_s_barrier();

    // ---- K loop: 16 K-tiles of 32; 3-kt lookahead, vmcnt(8) checkpoints.
    // NO lgkmcnt / sched_barrier between reads and MFMA — compiler inserts
    // fine-grained counted waits per dependency.
    #pragma unroll
    for (int kt = 0; kt < 16; ++kt) {
        const int s = kt & 3;
        short8 a[4], b[4];
        #pragma unroll
        for (int f = 0; f < 4; ++f) a[f] = rdA(s, f);
        #pragma unroll
        for (int n = 0; n < 4; ++n) b[n] = rdB(s, n);

        if (kt < 13) stage(kt + 3);              // set (kt+3)&3: read done @kt-1

        __builtin_amdgcn_s_setprio(1);
        #pragma unroll
        for (int f = 0; f < 4; ++f)
            #pragma unroll
            for (int n = 0; n < 4; ++n)
                acc[f][n] = MFMA(a[f], b[n], acc[f][n]);
        __builtin_amdgcn_s_setprio(0);

        // ensure stage(kt+1) landed before next iter reads it
        if (kt < 13)       asm volatile("s_waitcnt vmcnt(8)" ::: "memory");
        else if (kt == 13) asm volatile("s_waitcnt vmcnt(4)" ::: "memory");
        else if (kt == 14) asm volatile("s_waitcnt vmcnt(0)" ::: "memory");
        __builtin_amdgcn_s_barrier();
    }

    // ---- epilogue: C write + bias (fp32)
    const int crow = lg << 2;
    #pragma unroll
    for (int n = 0; n < 4; ++n) {
        int col = n0 + wc * 64 + n * 16 + lr;
        float bv = bias[col];
        #pragma unroll
        for (int f = 0; f < 4; ++f) {
            size_t rbase = (size_t)(m0 + wr * 64 + f * 16 + crow) * N + col;
            #pragma unroll
            for (int r = 0; r < 4; ++r)
                out[rbase + (size_t)r * N] = acc[f][n][r] + bv;
        }
    }
}

// ---------------------------------------------------------------------------
extern "C" void kernel_launch(void* const* d_in, const int* in_sizes, int n_in,
                              void* d_out, int out_size, void* d_ws, size_t ws_size,
                              hipStream_t stream) {
    const float* x    = (const float*)d_in[0];
    const float* W    = (const float*)d_in[1];
    const float* bias = (const float*)d_in[2];
    float* out = (float*)d_out;

    bf16* Wb   = (bf16*)d_ws;                          // 1MB
    bf16* Amat = (bf16*)((char*)d_ws + (1 << 21));     // 64MB at +2MB

    hipLaunchKernelGGL(ewma_kernel, dim3(B_SZ * 32), dim3(512), 0, stream,
                       x, W, Wb, Amat);
    hipLaunchKernelGGL(gemm_kernel,
                       dim3((B_SZ * T_LEN / 128) * (D_MODEL_ / 128)),
                       dim3(256), 65536, stream, Amat, Wb, bias, out);
}